// Round 15
// baseline (1328.721 us; speedup 1.0000x reference)
//
#include <hip/hip_runtime.h>

#define N_NODES 10000
#define N_EDGES 160000
#define NB 64
#define D 640
#define ND_IN 4
#define ED_IN 8
#define NLAYERS 6
#define M_ROWS (2 * N_NODES)  // both graphs batched

#define SCORE_SCALE 0.039528470752104741f  // 1/sqrt(640)
#define EXP_SHIFT 8.0f                     // constant softmax shift (invariant)
#define DBINS 64

typedef __attribute__((ext_vector_type(4))) float floatx4;
typedef __attribute__((ext_vector_type(2))) float floatx2;

__device__ __forceinline__ unsigned short f2bf(float f) {
  unsigned u = __float_as_uint(f);
  u += 0x7fffu + ((u >> 16) & 1);  // RNE
  return (unsigned short)(u >> 16);
}
__device__ __forceinline__ float bf2f(unsigned short s) {
  return __uint_as_float((unsigned)s << 16);
}
__device__ __forceinline__ void gload_lds16(const void* g, void* l) {
  __builtin_amdgcn_global_load_lds(
      (const __attribute__((address_space(1))) void*)g,
      (__attribute__((address_space(3))) void*)l, 16, 0, 0);
}
__device__ __forceinline__ float4 cvt4(ushort4 s) {
  return make_float4(bf2f(s.x), bf2f(s.y), bf2f(s.z), bf2f(s.w));
}
__device__ __forceinline__ float4 fp8x4_to_f4(unsigned u) {
  floatx2 lo = __builtin_amdgcn_cvt_pk_f32_fp8((int)u, false);
  floatx2 hi = __builtin_amdgcn_cvt_pk_f32_fp8((int)u, true);
  return make_float4(lo[0], lo[1], hi[0], hi[1]);
}
__device__ __forceinline__ unsigned f4_to_fp8x4(float a, float b, float c, float d) {
  int pk = __builtin_amdgcn_cvt_pk_fp8_f32(a, b, 0, false);
  pk = __builtin_amdgcn_cvt_pk_fp8_f32(c, d, pk, true);
  return (unsigned)pk;
}
__device__ __forceinline__ unsigned char f2fp8(float a) {
  return (unsigned char)(__builtin_amdgcn_cvt_pk_fp8_f32(a, 0.f, 0, false) & 0xFF);
}

// kv layout (fine-interleaved): node row = 2*D bytes; d-quad c (=d>>2) holds
// k[4c..4c+3] at byte 8c and v[4c..4c+3] at byte 8c+4.

// ---- layer-0 projections: q,skip bf16; k,v fp8 interleaved in kvf8 ----
__global__ void k_lin4(const float* __restrict__ xI, const float* __restrict__ xJ,
                       const float* __restrict__ Wq, const float* __restrict__ bq,
                       const float* __restrict__ Wk, const float* __restrict__ bk,
                       const float* __restrict__ Wv, const float* __restrict__ bv,
                       const float* __restrict__ Ws, const float* __restrict__ bs,
                       unsigned short* __restrict__ oqb, unsigned char* __restrict__ okv,
                       unsigned short* __restrict__ osb) {
  int t = blockIdx.x * blockDim.x + threadIdx.x;
  if (t >= M_ROWS * D) return;
  int z = blockIdx.z;
  const float* W = (z == 0) ? Wq : (z == 1) ? Wk : (z == 2) ? Wv : Ws;
  const float* b = (z == 0) ? bq : (z == 1) ? bk : (z == 2) ? bv : bs;
  int n = t / D, d = t % D;
  const float* xr = (n < N_NODES) ? xI + (size_t)n * ND_IN
                                  : xJ + (size_t)(n - N_NODES) * ND_IN;
  float acc = b[d];
#pragma unroll
  for (int c = 0; c < ND_IN; ++c) acc += xr[c] * W[c * D + d];
  if (z == 0) oqb[t] = f2bf(acc);
  else if (z == 3) osb[t] = f2bf(acc);
  else
    okv[(size_t)n * 2 * D + (d >> 2) * 8 + (d & 3) + ((z == 2) ? 4 : 0)] = f2fp8(acc);
}

// one-time: Wt8[l][mat][n][k] = fp8(W[l][mat][k][n])
__global__ __launch_bounds__(256) void k_wprep(const float* __restrict__ Wq,
                                               const float* __restrict__ Wk,
                                               const float* __restrict__ Wv,
                                               const float* __restrict__ Ws,
                                               unsigned char* __restrict__ Wt8) {
  __shared__ float tile[32][33];
  int mt = blockIdx.z;
  int l = mt >> 2, mat = mt & 3;
  const float* W =
      (mat == 0 ? Wq : mat == 1 ? Wk : mat == 2 ? Wv : Ws) + (size_t)l * D * D;
  int tk = blockIdx.x * 32, tn = blockIdx.y * 32;
  int tx = threadIdx.x & 31, ty = threadIdx.x >> 5;
#pragma unroll
  for (int i = 0; i < 32; i += 8)
    tile[ty + i][tx] = W[(size_t)(tk + ty + i) * D + tn + tx];
  __syncthreads();
  unsigned char* dst = Wt8 + (size_t)mt * D * D;
#pragma unroll
  for (int i = 0; i < 32; i += 8)
    dst[(size_t)(tn + ty + i) * D + tk + tx] = f2fp8(tile[tx][ty + i]);
}

// fp8 MFMA GEMM over 2N rows, XCD-swizzled flat grid, BK=128 bytes (5 K-iters,
// 64 MFMA per barrier), swapped-operand epilogue (row=l15, col=l4*4+reg).
#define BM 128
#define BN 128
#define BKF 128
#define RBANDS ((M_ROWS + BM - 1) / BM)  // 157
__global__ __launch_bounds__(256) void k_gemm_fp8(
    const unsigned char* __restrict__ Af8, const unsigned char* __restrict__ Wt8,
    const float* __restrict__ b0, const float* __restrict__ b1,
    const float* __restrict__ b2, const float* __restrict__ b3,
    unsigned short* __restrict__ oqb, unsigned char* __restrict__ okv,
    unsigned short* __restrict__ osb) {
  __shared__ __attribute__((aligned(16))) unsigned char lA[BM * BKF];  // 16 KB
  __shared__ __attribute__((aligned(16))) unsigned char lB[BN * BKF];  // 16 KB
  const int f = blockIdx.x;
  const int xcd = f & 7;
  const int slot = f >> 3;
  const int grp = slot / 20;
  const int tt = slot - grp * 20;  // 0..19
  const int r = xcd + (grp << 3);
  if (r >= RBANDS) return;
  const int z = tt / 5;
  const int by = tt - z * 5;
  const unsigned char* Wz = Wt8 + (size_t)z * D * D;
  const float* bias = (z == 0) ? b0 : (z == 1) ? b1 : (z == 2) ? b2 : b3;
  const int bm = r * BM, bn = by * BN;
  const int t = threadIdx.x;
  const int lane = t & 63, wv = t >> 6;
  const int wm = (wv & 1) * 64, wn = (wv >> 1) * 64;
  const int l15 = lane & 15, l4 = lane >> 4;
  const int srow = lane >> 3;
  const int scb = lane & 7;

  floatx4 acc[4][4] = {};  // [ni][mi]

  for (int k0 = 0; k0 < D; k0 += BKF) {  // 5 iterations
#pragma unroll
    for (int i = 0; i < 4; ++i) {
      int row = wv * 32 + i * 8 + srow;
      int lcb = scb ^ (row & 7);
      gload_lds16(Af8 + (size_t)(bm + row) * D + k0 + lcb * 16,
                  lA + (size_t)(wv * 32 + i * 8) * BKF);
      gload_lds16(Wz + (size_t)(bn + row) * D + k0 + lcb * 16,
                  lB + (size_t)(wv * 32 + i * 8) * BKF);
    }
    __syncthreads();
#pragma unroll
    for (int kk = 0; kk < 4; ++kk) {
      long af[4], bfr[4];
      int c8 = kk * 4 + l4;
      int blk = c8 >> 1, sub = (c8 & 1) * 8;
#pragma unroll
      for (int i = 0; i < 4; ++i) {
        int rowA = wm + i * 16 + l15;
        af[i] = *(const long*)(lA + (size_t)rowA * BKF +
                               (blk ^ (rowA & 7)) * 16 + sub);
        int rowB = wn + i * 16 + l15;
        bfr[i] = *(const long*)(lB + (size_t)rowB * BKF +
                                (blk ^ (rowB & 7)) * 16 + sub);
      }
#pragma unroll
      for (int ni = 0; ni < 4; ++ni)
#pragma unroll
        for (int mi = 0; mi < 4; ++mi)
          acc[ni][mi] = __builtin_amdgcn_mfma_f32_16x16x32_fp8_fp8(
              bfr[ni], af[mi], acc[ni][mi], 0, 0, 0);
    }
    __syncthreads();
  }
  float4 bia[4];
#pragma unroll
  for (int ni = 0; ni < 4; ++ni)
    bia[ni] = *(const float4*)(bias + bn + wn + ni * 16 + l4 * 4);
#pragma unroll
  for (int mi = 0; mi < 4; ++mi) {
    int row = bm + wm + mi * 16 + l15;
    if (row >= M_ROWS) continue;
#pragma unroll
    for (int ni = 0; ni < 4; ++ni) {
      int col = bn + wn + ni * 16 + l4 * 4;
      float v0 = acc[ni][mi][0] + bia[ni].x;
      float v1 = acc[ni][mi][1] + bia[ni].y;
      float v2 = acc[ni][mi][2] + bia[ni].z;
      float v3 = acc[ni][mi][3] + bia[ni].w;
      if (z == 0 || z == 3) {
        ushort4 pk;
        pk.x = f2bf(v0);
        pk.y = f2bf(v1);
        pk.z = f2bf(v2);
        pk.w = f2bf(v3);
        unsigned short* dst = (z == 0) ? oqb : osb;
        *(ushort4*)(dst + (size_t)row * D + col) = pk;
      } else {
        unsigned pk8 = f4_to_fp8x4(v0, v1, v2, v3);
        *(unsigned*)(okv + (size_t)row * 2 * D + col * 2 + ((z == 2) ? 4 : 0)) = pk8;
      }
    }
  }
}

// ---- combined-graph CSR build ----
__global__ void k_hist(const int* __restrict__ dstI, const int* __restrict__ dstJ,
                       int* __restrict__ cnt) {
  int e = blockIdx.x * blockDim.x + threadIdx.x;
  if (e >= 2 * N_EDGES) return;
  int d = (e < N_EDGES) ? dstI[e] : (dstJ[e - N_EDGES] + N_NODES);
  atomicAdd(&cnt[d], 1);
}

__global__ __launch_bounds__(1024) void k_scan(const int* __restrict__ cnt,
                                               int* __restrict__ start,
                                               int* __restrict__ cursor) {
  __shared__ int sh[1024];
  __shared__ int carry_sh;
  int tid = threadIdx.x;
  if (tid == 0) {
    carry_sh = 0;
    start[0] = 0;
  }
  __syncthreads();
  for (int base = 0; base < M_ROWS; base += 1024) {
    int idx = base + tid;
    int v = (idx < M_ROWS) ? cnt[idx] : 0;
    sh[tid] = v;
    __syncthreads();
    for (int off = 1; off < 1024; off <<= 1) {
      int t = (tid >= off) ? sh[tid - off] : 0;
      __syncthreads();
      sh[tid] += t;
      __syncthreads();
    }
    int incl = sh[tid] + carry_sh;
    if (idx < M_ROWS) {
      start[idx + 1] = incl;
      cursor[idx] = incl - v;
    }
    __syncthreads();
    if (tid == 1023) carry_sh = incl;
    __syncthreads();
  }
}

// scatter + gather edge attrs into CSR order (eaS)
__global__ void k_scatter(const int* __restrict__ srcI, const int* __restrict__ dstI,
                          const int* __restrict__ srcJ, const int* __restrict__ dstJ,
                          const float* __restrict__ eaI, const float* __restrict__ eaJ,
                          int* __restrict__ cursor, int* __restrict__ srcS,
                          float* __restrict__ eaS) {
  int e = blockIdx.x * blockDim.x + threadIdx.x;
  if (e >= 2 * N_EDGES) return;
  int s, d;
  const float* eap;
  if (e < N_EDGES) {
    s = srcI[e];
    d = dstI[e];
    eap = eaI + (size_t)e * ED_IN;
  } else {
    s = srcJ[e - N_EDGES] + N_NODES;
    d = dstJ[e - N_EDGES] + N_NODES;
    eap = eaJ + (size_t)(e - N_EDGES) * ED_IN;
  }
  int pos = atomicAdd(&cursor[d], 1);
  srcS[pos] = s;
  float4 a0 = *(const float4*)eap;
  float4 a1 = *(const float4*)(eap + 4);
  *(float4*)(eaS + (size_t)pos * ED_IN) = a0;
  *(float4*)(eaS + (size_t)pos * ED_IN + 4) = a1;
}

// ---- degree-balanced node permutation (counting sort by degree) ----
__global__ void k_dhist(const int* __restrict__ start, int* __restrict__ dbins) {
  int w = blockIdx.x * blockDim.x + threadIdx.x;
  if (w >= M_ROWS) return;
  int deg = start[w + 1] - start[w];
  atomicAdd(&dbins[min(deg, DBINS - 1)], 1);
}

__global__ void k_dscan(const int* __restrict__ dbins, int* __restrict__ dcur) {
  // single wave: exclusive prefix over 64 bins
  int tid = threadIdx.x;
  int v = dbins[tid];
  int ex = 0;
#pragma unroll
  for (int off = 1; off < 64; off <<= 1) {
    int t = __shfl_up(v, off);
    if (tid >= off) v += t;
  }
  ex = v - dbins[tid];
  dcur[tid] = ex;
}

__global__ void k_dscatter(const int* __restrict__ start, int* __restrict__ dcur,
                           int* __restrict__ nodePerm) {
  int w = blockIdx.x * blockDim.x + threadIdx.x;
  if (w >= M_ROWS) return;
  int deg = start[w + 1] - start[w];
  int pos = atomicAdd(&dcur[min(deg, DBINS - 1)], 1);
  nodePerm[pos] = w;
}

// ---- fused edge phase: one wave per node (degree-sorted assignment); two
// 32-lane groups split the edge list (stride 2), each unrolled by 2, srcS
// prefetch; fp8 kv gathers as 5 x uint2; constant-shift softmax; add merge.
__global__ __launch_bounds__(256) void k_edge_fused(
    unsigned char* __restrict__ hf8, unsigned short* __restrict__ hbf,
    const unsigned short* __restrict__ sbf, const unsigned short* __restrict__ qb16,
    const unsigned char* __restrict__ kvf8, const float* __restrict__ eaS,
    const float* __restrict__ We, const int* __restrict__ srcS,
    const int* __restrict__ start, const int* __restrict__ nodePerm,
    int do_relu, int write_bf) {
  int idx = blockIdx.x * 4 + (threadIdx.x >> 6);
  if (idx >= M_ROWS) return;
  int w = nodePerm[idx];
  int l64 = threadIdx.x & 63;
  int g = l64 >> 5, lane = l64 & 31;
  const int s0 = start[w], s1 = start[w + 1];
  const int deg = s1 - s0;
  const int EMAX = 2 * N_EDGES - 1;

  float4 qr[5];
#pragma unroll
  for (int i = 0; i < 5; ++i)
    qr[i] = cvt4(*(const ushort4*)(qb16 + (size_t)w * D + i * 128 + 4 * lane));

  // Gc split: group g computes c = 4g+j (j=0..3), shared via width-64 shfl.
  float gv = 0.f;
#pragma unroll
  for (int j = 0; j < 4; ++j) {
    const float* wr = We + (4 * g + j) * D;
    float p = 0.f;
#pragma unroll
    for (int i = 0; i < 5; ++i) {
      float4 wv = *(const float4*)(wr + i * 128 + 4 * lane);
      p += qr[i].x * wv.x + qr[i].y * wv.y + qr[i].z * wv.z + qr[i].w * wv.w;
    }
#pragma unroll
    for (int m = 1; m < 32; m <<= 1) p += __shfl_xor(p, m, 32);
    if (lane == j) gv = p;
  }
  float Gc = 0.f;
  {
    int src = (lane < 4) ? lane : (32 + lane - 4);
    float tg = __shfl(gv, src, 64);
    if (lane < ED_IN) Gc = tg;
  }

  float Sp = 0.f, Sea = 0.f;
  float4 acc[5];
#pragma unroll
  for (int i = 0; i < 5; ++i) acc[i] = make_float4(0.f, 0.f, 0.f, 0.f);

  int p0 = s0 + g, p1 = p0 + 2;
  int c0 = min(p0, EMAX), c1 = min(p1, EMAX);
  int sj0 = srcS[c0], sj1 = srcS[c1];
  const int U = (deg + 3) >> 2;
  for (int u = 0; u < U; ++u) {
    bool ok0 = p0 < s1, ok1 = p1 < s1;
    int cc0 = c0, cc1 = c1;
    int tj0 = sj0, tj1 = sj1;
    p0 += 4;
    p1 += 4;
    c0 = min(p0, EMAX);
    c1 = min(p1, EMAX);
    sj0 = srcS[c0];
    sj1 = srcS[c1];

    const unsigned char* r0 = kvf8 + (size_t)tj0 * 2 * D;
    const unsigned char* r1 = kvf8 + (size_t)tj1 * 2 * D;
    uint2 kv0[5], kv1[5];
#pragma unroll
    for (int i = 0; i < 5; ++i) {
      int off = i * 256 + lane * 8;
      kv0[i] = *(const uint2*)(r0 + off);
      kv1[i] = *(const uint2*)(r1 + off);
    }
    float ea0 = (lane < ED_IN) ? eaS[(size_t)cc0 * ED_IN + lane] : 0.f;
    float ea1 = (lane < ED_IN) ? eaS[(size_t)cc1 * ED_IN + lane] : 0.f;
    float part0 = ea0 * Gc, part1 = ea1 * Gc;
#pragma unroll
    for (int i = 0; i < 5; ++i) {
      float4 k0 = fp8x4_to_f4(kv0[i].x);
      float4 k1 = fp8x4_to_f4(kv1[i].x);
      part0 += qr[i].x * k0.x + qr[i].y * k0.y + qr[i].z * k0.z + qr[i].w * k0.w;
      part1 += qr[i].x * k1.x + qr[i].y * k1.y + qr[i].z * k1.z + qr[i].w * k1.w;
    }
#pragma unroll
    for (int m = 1; m < 32; m <<= 1) {
      part0 += __shfl_xor(part0, m, 32);
      part1 += __shfl_xor(part1, m, 32);
    }
    float pA = ok0 ? __expf(part0 * SCORE_SCALE - EXP_SHIFT) : 0.f;
    float pB = ok1 ? __expf(part1 * SCORE_SCALE - EXP_SHIFT) : 0.f;
    Sp += pA + pB;
    Sea += pA * ea0 + pB * ea1;
#pragma unroll
    for (int i = 0; i < 5; ++i) {
      float4 v0 = fp8x4_to_f4(kv0[i].y);
      float4 v1 = fp8x4_to_f4(kv1[i].y);
      acc[i].x += pA * v0.x + pB * v1.x;
      acc[i].y += pA * v0.y + pB * v1.y;
      acc[i].z += pA * v0.z + pB * v1.z;
      acc[i].w += pA * v0.w + pB * v1.w;
    }
  }

  // merge the two groups' sums (plain adds — no max state)
  Sp += __shfl_xor(Sp, 32);
  Sea += __shfl_xor(Sea, 32);
#pragma unroll
  for (int i = 0; i < 5; ++i) {
    acc[i].x += __shfl_xor(acc[i].x, 32);
    acc[i].y += __shfl_xor(acc[i].y, 32);
    acc[i].z += __shfl_xor(acc[i].z, 32);
    acc[i].w += __shfl_xor(acc[i].w, 32);
  }
  float inv = 1.0f / (Sp + 1e-16f);
  float seac[ED_IN];
#pragma unroll
  for (int c = 0; c < ED_IN; ++c) seac[c] = __shfl(Sea, c, 32);

  for (int i = g; i < 5; i += 2) {
    int d = i * 128 + 4 * lane;
    float4 term = acc[i];
#pragma unroll
    for (int c = 0; c < ED_IN; ++c) {
      float4 wv = *(const float4*)(We + c * D + d);
      term.x += seac[c] * wv.x;
      term.y += seac[c] * wv.y;
      term.z += seac[c] * wv.z;
      term.w += seac[c] * wv.w;
    }
    ushort4 sv = *(const ushort4*)(sbf + (size_t)w * D + d);
    float vx = bf2f(sv.x) + term.x * inv;
    float vy = bf2f(sv.y) + term.y * inv;
    float vz = bf2f(sv.z) + term.z * inv;
    float vw = bf2f(sv.w) + term.w * inv;
    if (do_relu) {
      vx = fmaxf(vx, 0.f);
      vy = fmaxf(vy, 0.f);
      vz = fmaxf(vz, 0.f);
      vw = fmaxf(vw, 0.f);
    }
    if (write_bf) {
      ushort4 hb;
      hb.x = f2bf(vx);
      hb.y = f2bf(vy);
      hb.z = f2bf(vz);
      hb.w = f2bf(vw);
      *(ushort4*)(hbf + (size_t)w * D + d) = hb;
    } else {
      *(unsigned*)(hf8 + (size_t)w * D + d) = f4_to_fp8x4(vx, vy, vz, vw);
    }
  }
}

// per-batch node ranges via binary search (batch arrays are sorted)
__global__ void k_ranges(const int* __restrict__ batI, const int* __restrict__ batJ,
                         int* __restrict__ rng) {
  int b = threadIdx.x;
  if (b > 2 * NB) return;
  if (b == 2 * NB) {
    rng[b] = M_ROWS;
    return;
  }
  const int* bat = (b < NB) ? batI : batJ;
  int tgt = (b < NB) ? b : b - NB;
  int lo = 0, hi = N_NODES;
  while (lo < hi) {
    int mid = (lo + hi) >> 1;
    if (bat[mid] < tgt) lo = mid + 1;
    else hi = mid;
  }
  rng[b] = lo + ((b < NB) ? 0 : N_NODES);
}

// segmented pool: block b sums rows [rng[b], rng[b+1]) — no atomics
__global__ __launch_bounds__(256) void k_pool_seg(const unsigned short* __restrict__ hbf,
                                                  const int* __restrict__ rng,
                                                  float* __restrict__ pooled) {
  int b = blockIdx.x;
  int lo = rng[b], hi = rng[b + 1];
  int ch = threadIdx.x;  // ushort4 chunk id, 0..159
  if (ch >= 160) return;
  float4 s = make_float4(0.f, 0.f, 0.f, 0.f);
  for (int n = lo; n < hi; ++n) {
    ushort4 v = *(const ushort4*)(hbf + (size_t)n * D + ch * 4);
    s.x += bf2f(v.x);
    s.y += bf2f(v.y);
    s.z += bf2f(v.z);
    s.w += bf2f(v.w);
  }
  *(float4*)(pooled + (size_t)b * D + ch * 4) = s;
}

// head: LayerNorm -> @Wemb + bemb -> ReLU.  grid (2NB, 5), 128 threads.
__global__ __launch_bounds__(128) void k_head(const float* __restrict__ pooled,
                                              const float* __restrict__ gam,
                                              const float* __restrict__ bet,
                                              const float* __restrict__ Wemb,
                                              const float* __restrict__ bemb,
                                              float* __restrict__ z) {
  __shared__ float sh[D];
  __shared__ float red[2];
  int b = blockIdx.x, seg = blockIdx.y, tid = threadIdx.x;
  float local = 0.f;
#pragma unroll
  for (int c = tid; c < D; c += 128) {
    float val = pooled[(size_t)b * D + c];
    sh[c] = val;
    local += val;
  }
#pragma unroll
  for (int off = 32; off > 0; off >>= 1) local += __shfl_down(local, off);
  if ((tid & 63) == 0) red[tid >> 6] = local;
  __syncthreads();
  float mu = (red[0] + red[1]) * (1.0f / D);
  __syncthreads();
  float lv = 0.f;
#pragma unroll
  for (int c = tid; c < D; c += 128) {
    float t2 = sh[c] - mu;
    lv += t2 * t2;
  }
#pragma unroll
  for (int off = 32; off > 0; off >>= 1) lv += __shfl_down(lv, off);
  if ((tid & 63) == 0) red[tid >> 6] = lv;
  __syncthreads();
  float var = (red[0] + red[1]) * (1.0f / D);
  float rstd = rsqrtf(var + 1e-5f);
  __syncthreads();
#pragma unroll
  for (int c = tid; c < D; c += 128) sh[c] = (sh[c] - mu) * rstd * gam[c] + bet[c];
  __syncthreads();
  int d = seg * 128 + tid;
  float a0 = 0.f, a1 = 0.f, a2 = 0.f, a3 = 0.f;
  for (int c = 0; c < D; c += 4) {
    a0 += sh[c] * Wemb[(size_t)c * D + d];
    a1 += sh[c + 1] * Wemb[(size_t)(c + 1) * D + d];
    a2 += sh[c + 2] * Wemb[(size_t)(c + 2) * D + d];
    a3 += sh[c + 3] * Wemb[(size_t)(c + 3) * D + d];
  }
  z[(size_t)b * D + d] = fmaxf((a0 + a1) + (a2 + a3) + bemb[d], 0.f);
}

__global__ void k_cosine(const float* __restrict__ zi, const float* __restrict__ zj,
                         float* __restrict__ out) {
  int b = blockIdx.x, lane = threadIdx.x;
  float dot = 0.f, ni = 0.f, nj = 0.f;
  for (int d = lane; d < D; d += 64) {
    float a = zi[(size_t)b * D + d], c = zj[(size_t)b * D + d];
    dot += a * c;
    ni += a * a;
    nj += c * c;
  }
#pragma unroll
  for (int off = 32; off > 0; off >>= 1) {
    dot += __shfl_down(dot, off);
    ni += __shfl_down(ni, off);
    nj += __shfl_down(nj, off);
  }
  if (lane == 0)
    out[b] = dot / (fmaxf(sqrtf(ni), 1e-8f) * fmaxf(sqrtf(nj), 1e-8f));
}

extern "C" void kernel_launch(void* const* d_in, const int* in_sizes, int n_in,
                              void* d_out, int out_size, void* d_ws, size_t ws_size,
                              hipStream_t stream) {
  (void)in_sizes; (void)n_in; (void)out_size; (void)ws_size;
  const float* xI = (const float*)d_in[0];
  const int* eiI = (const int*)d_in[1];
  const float* eaI = (const float*)d_in[2];
  const int* batI = (const int*)d_in[3];
  const float* xJ = (const float*)d_in[4];
  const int* eiJ = (const int*)d_in[5];
  const float* eaJ = (const float*)d_in[6];
  const int* batJ = (const int*)d_in[7];
  const float* W0q = (const float*)d_in[8];
  const float* b0q = (const float*)d_in[9];
  const float* W0k = (const float*)d_in[10];
  const float* b0k = (const float*)d_in[11];
  const float* W0v = (const float*)d_in[12];
  const float* b0v = (const float*)d_in[13];
  const float* W0e = (const float*)d_in[14];
  const float* W0s = (const float*)d_in[15];
  const float* b0s = (const float*)d_in[16];
  const float* Wq = (const float*)d_in[17];
  const float* bq = (const float*)d_in[18];
  const float* Wk = (const float*)d_in[19];
  const float* bk = (const float*)d_in[20];
  const float* Wv = (const float*)d_in[21];
  const float* bv = (const float*)d_in[22];
  const float* We = (const float*)d_in[23];
  const float* Ws = (const float*)d_in[24];
  const float* bs = (const float*)d_in[25];
  const float* ln_g = (const float*)d_in[26];
  const float* ln_b = (const float*)d_in[27];
  const float* Wemb = (const float*)d_in[28];
  const float* bemb = (const float*)d_in[29];

  const size_t ND2 = (size_t)M_ROWS * D;
  float* pooled = (float*)d_ws;                  // 2NB*D
  float* z = pooled + (size_t)2 * NB * D;        // 2NB*D
  float* eaS = z + (size_t)2 * NB * D;           // 2E*8
  unsigned short* qbf = (unsigned short*)(eaS + (size_t)2 * N_EDGES * ED_IN);
  unsigned char* kvf8 = (unsigned char*)(qbf + ND2);   // 2*ND2 bytes
  unsigned char* hf8 = kvf8 + 2 * ND2;                 // ND2 bytes
  unsigned short* hbf = (unsigned short*)(hf8 + ND2);  // ND2
  unsigned short* sbf = hbf + ND2;               // ND2
  unsigned char* Wt8 = (unsigned char*)(sbf + ND2);    // 20*D*D bytes
  int* cnt = (int*)(Wt8 + (size_t)(NLAYERS - 1) * 4 * D * D);  // 2N
  int* start = cnt + M_ROWS;                     // 2N+1
  int* cursor = start + M_ROWS + 1;              // 2N
  int* srcS = cursor + M_ROWS;                   // 2E
  int* rng = srcS + 2 * N_EDGES;                 // 2NB+1
  int* nodePerm = rng + 2 * NB + 1;              // 2N
  int* dbins = nodePerm + M_ROWS;                // 64
  int* dcur = dbins + DBINS;                     // 64

  const int* srcI = eiI;
  const int* dstI = eiI + N_EDGES;
  const int* srcJ = eiJ;
  const int* dstJ = eiJ + N_EDGES;

  dim3 gLin4((M_ROWS * D + 255) / 256, 1, 4);
  dim3 gGemm(8 * 20 * 20);
  dim3 gEdge((M_ROWS + 3) / 4);
  dim3 gE((2 * N_EDGES + 255) / 256);
  dim3 gNode((M_ROWS + 255) / 256);

  k_wprep<<<dim3(D / 32, D / 32, (NLAYERS - 1) * 4), 256, 0, stream>>>(Wq, Wk, Wv, Ws, Wt8);

  // combined CSR (+ ea gather) + degree-sorted node permutation + batch ranges
  hipMemsetAsync(cnt, 0, M_ROWS * sizeof(int), stream);
  hipMemsetAsync(dbins, 0, DBINS * sizeof(int), stream);
  k_hist<<<gE, 256, 0, stream>>>(dstI, dstJ, cnt);
  k_scan<<<1, 1024, 0, stream>>>(cnt, start, cursor);
  k_scatter<<<gE, 256, 0, stream>>>(srcI, dstI, srcJ, dstJ, eaI, eaJ, cursor,
                                    srcS, eaS);
  k_dhist<<<gNode, 256, 0, stream>>>(start, dbins);
  k_dscan<<<1, 64, 0, stream>>>(dbins, dcur);
  k_dscatter<<<gNode, 256, 0, stream>>>(start, dcur, nodePerm);
  k_ranges<<<1, 192, 0, stream>>>(batI, batJ, rng);

  // layer 0
  k_lin4<<<gLin4, 256, 0, stream>>>(xI, xJ, W0q, b0q, W0k, b0k, W0v, b0v, W0s,
                                    b0s, qbf, kvf8, sbf);
  k_edge_fused<<<gEdge, 256, 0, stream>>>(hf8, hbf, sbf, qbf, kvf8, eaS, W0e,
                                          srcS, start, nodePerm, 1, 0);

  // layers 1..5
  for (int l = 0; l < NLAYERS - 1; ++l) {
    const unsigned char* WtL = Wt8 + (size_t)l * 4 * D * D;
    const float* Wel = We + (size_t)l * ED_IN * D;
    int last = (l == NLAYERS - 2);
    k_gemm_fp8<<<gGemm, 256, 0, stream>>>(
        hf8, WtL, bq + (size_t)l * D, bk + (size_t)l * D, bv + (size_t)l * D,
        bs + (size_t)l * D, qbf, kvf8, sbf);
    k_edge_fused<<<gEdge, 256, 0, stream>>>(hf8, hbf, sbf, qbf, kvf8, eaS, Wel,
                                            srcS, start, nodePerm,
                                            last ? 0 : 1, last ? 1 : 0);
  }

  k_pool_seg<<<2 * NB, 256, 0, stream>>>(hbf, rng, pooled);
  k_head<<<dim3(2 * NB, 5), 128, 0, stream>>>(pooled, ln_g, ln_b, Wemb, bemb, z);
  k_cosine<<<NB, 64, 0, stream>>>(z, z + (size_t)NB * D, (float*)d_out);
}

// Round 16
// 1151.930 us; speedup vs baseline: 1.1535x; 1.1535x over previous
//
#include <hip/hip_runtime.h>

#define N_NODES 10000
#define N_EDGES 160000
#define NB 64
#define D 640
#define ND_IN 4
#define ED_IN 8
#define NLAYERS 6
#define M_ROWS (2 * N_NODES)  // both graphs batched

#define SCORE_SCALE 0.039528470752104741f  // 1/sqrt(640)
#define NEGBIG -3.4e38f

typedef __attribute__((ext_vector_type(4))) float floatx4;
typedef __attribute__((ext_vector_type(2))) float floatx2;

__device__ __forceinline__ unsigned short f2bf(float f) {
  unsigned u = __float_as_uint(f);
  u += 0x7fffu + ((u >> 16) & 1);  // RNE
  return (unsigned short)(u >> 16);
}
__device__ __forceinline__ float bf2f(unsigned short s) {
  return __uint_as_float((unsigned)s << 16);
}
__device__ __forceinline__ void gload_lds16(const void* g, void* l) {
  __builtin_amdgcn_global_load_lds(
      (const __attribute__((address_space(1))) void*)g,
      (__attribute__((address_space(3))) void*)l, 16, 0, 0);
}
__device__ __forceinline__ float4 cvt4(ushort4 s) {
  return make_float4(bf2f(s.x), bf2f(s.y), bf2f(s.z), bf2f(s.w));
}
// 4 fp8 e4m3 (packed in uint) -> float4 via v_cvt_pk_f32_fp8
__device__ __forceinline__ float4 fp8x4_to_f4(unsigned u) {
  floatx2 lo = __builtin_amdgcn_cvt_pk_f32_fp8((int)u, false);
  floatx2 hi = __builtin_amdgcn_cvt_pk_f32_fp8((int)u, true);
  return make_float4(lo[0], lo[1], hi[0], hi[1]);
}
// 4 floats -> packed fp8 e4m3 uint via v_cvt_pk_fp8_f32
__device__ __forceinline__ unsigned f4_to_fp8x4(float a, float b, float c, float d) {
  int pk = __builtin_amdgcn_cvt_pk_fp8_f32(a, b, 0, false);
  pk = __builtin_amdgcn_cvt_pk_fp8_f32(c, d, pk, true);
  return (unsigned)pk;
}
__device__ __forceinline__ unsigned char f2fp8(float a) {
  return (unsigned char)(__builtin_amdgcn_cvt_pk_fp8_f32(a, 0.f, 0, false) & 0xFF);
}

// kv layout: k at row 2n, v at row 2n+1 (each D fp8 bytes).

// ---- layer-0 projections, single fused pass: q,skip bf16; k,v fp8 ----
__global__ void k_lin4(const float* __restrict__ xI, const float* __restrict__ xJ,
                       const float* __restrict__ Wq, const float* __restrict__ bq,
                       const float* __restrict__ Wk, const float* __restrict__ bk,
                       const float* __restrict__ Wv, const float* __restrict__ bv,
                       const float* __restrict__ Ws, const float* __restrict__ bs,
                       unsigned short* __restrict__ oqb, unsigned char* __restrict__ okv,
                       unsigned short* __restrict__ osb) {
  int t = blockIdx.x * blockDim.x + threadIdx.x;
  if (t >= M_ROWS * D) return;
  int n = t / D, d = t % D;
  const float* xr = (n < N_NODES) ? xI + (size_t)n * ND_IN
                                  : xJ + (size_t)(n - N_NODES) * ND_IN;
  float x0 = xr[0], x1 = xr[1], x2 = xr[2], x3 = xr[3];
  float aq = bq[d] + x0 * Wq[d] + x1 * Wq[D + d] + x2 * Wq[2 * D + d] + x3 * Wq[3 * D + d];
  float ak = bk[d] + x0 * Wk[d] + x1 * Wk[D + d] + x2 * Wk[2 * D + d] + x3 * Wk[3 * D + d];
  float av = bv[d] + x0 * Wv[d] + x1 * Wv[D + d] + x2 * Wv[2 * D + d] + x3 * Wv[3 * D + d];
  float as = bs[d] + x0 * Ws[d] + x1 * Ws[D + d] + x2 * Ws[2 * D + d] + x3 * Ws[3 * D + d];
  oqb[t] = f2bf(aq);
  osb[t] = f2bf(as);
  okv[(size_t)(2 * n) * D + d] = f2fp8(ak);
  okv[(size_t)(2 * n + 1) * D + d] = f2fp8(av);
}

// one-time: Wt8[l][mat][n][k] = fp8(W[l][mat][k][n])
__global__ __launch_bounds__(256) void k_wprep(const float* __restrict__ Wq,
                                               const float* __restrict__ Wk,
                                               const float* __restrict__ Wv,
                                               const float* __restrict__ Ws,
                                               unsigned char* __restrict__ Wt8) {
  __shared__ float tile[32][33];
  int mt = blockIdx.z;
  int l = mt >> 2, mat = mt & 3;
  const float* W =
      (mat == 0 ? Wq : mat == 1 ? Wk : mat == 2 ? Wv : Ws) + (size_t)l * D * D;
  int tk = blockIdx.x * 32, tn = blockIdx.y * 32;
  int tx = threadIdx.x & 31, ty = threadIdx.x >> 5;
#pragma unroll
  for (int i = 0; i < 32; i += 8)
    tile[ty + i][tx] = W[(size_t)(tk + ty + i) * D + tn + tx];
  __syncthreads();
  unsigned char* dst = Wt8 + (size_t)mt * D * D;
#pragma unroll
  for (int i = 0; i < 32; i += 8)
    dst[(size_t)(tn + ty + i) * D + tk + tx] = f2fp8(tile[tx][ty + i]);
}

// fp8 MFMA GEMM over 2N rows, XCD-swizzled flat grid, BK=128 bytes (5 K-iters,
// 64 MFMA per barrier), swapped-operand epilogue (row=l15, col=l4*4+reg).
#define BM 128
#define BN 128
#define BKF 128
#define RBANDS ((M_ROWS + BM - 1) / BM)  // 157
__global__ __launch_bounds__(256) void k_gemm_fp8(
    const unsigned char* __restrict__ Af8, const unsigned char* __restrict__ Wt8,
    const float* __restrict__ b0, const float* __restrict__ b1,
    const float* __restrict__ b2, const float* __restrict__ b3,
    unsigned short* __restrict__ oqb, unsigned char* __restrict__ okv,
    unsigned short* __restrict__ osb) {
  __shared__ __attribute__((aligned(16))) unsigned char lA[BM * BKF];  // 16 KB
  __shared__ __attribute__((aligned(16))) unsigned char lB[BN * BKF];  // 16 KB
  const int f = blockIdx.x;
  const int xcd = f & 7;
  const int slot = f >> 3;
  const int grp = slot / 20;
  const int tt = slot - grp * 20;  // 0..19
  const int r = xcd + (grp << 3);
  if (r >= RBANDS) return;
  const int z = tt / 5;
  const int by = tt - z * 5;
  const unsigned char* Wz = Wt8 + (size_t)z * D * D;
  const float* bias = (z == 0) ? b0 : (z == 1) ? b1 : (z == 2) ? b2 : b3;
  const int bm = r * BM, bn = by * BN;
  const int t = threadIdx.x;
  const int lane = t & 63, wv = t >> 6;
  const int wm = (wv & 1) * 64, wn = (wv >> 1) * 64;
  const int l15 = lane & 15, l4 = lane >> 4;
  const int srow = lane >> 3;
  const int scb = lane & 7;

  floatx4 acc[4][4] = {};  // [ni][mi]

  for (int k0 = 0; k0 < D; k0 += BKF) {  // 5 iterations
#pragma unroll
    for (int i = 0; i < 4; ++i) {
      int row = wv * 32 + i * 8 + srow;
      int lcb = scb ^ (row & 7);
      gload_lds16(Af8 + (size_t)(bm + row) * D + k0 + lcb * 16,
                  lA + (size_t)(wv * 32 + i * 8) * BKF);
      gload_lds16(Wz + (size_t)(bn + row) * D + k0 + lcb * 16,
                  lB + (size_t)(wv * 32 + i * 8) * BKF);
    }
    __syncthreads();
#pragma unroll
    for (int kk = 0; kk < 4; ++kk) {
      long af[4], bfr[4];
      int c8 = kk * 4 + l4;
      int blk = c8 >> 1, sub = (c8 & 1) * 8;
#pragma unroll
      for (int i = 0; i < 4; ++i) {
        int rowA = wm + i * 16 + l15;
        af[i] = *(const long*)(lA + (size_t)rowA * BKF +
                               (blk ^ (rowA & 7)) * 16 + sub);
        int rowB = wn + i * 16 + l15;
        bfr[i] = *(const long*)(lB + (size_t)rowB * BKF +
                                (blk ^ (rowB & 7)) * 16 + sub);
      }
#pragma unroll
      for (int ni = 0; ni < 4; ++ni)
#pragma unroll
        for (int mi = 0; mi < 4; ++mi)
          acc[ni][mi] = __builtin_amdgcn_mfma_f32_16x16x32_fp8_fp8(
              bfr[ni], af[mi], acc[ni][mi], 0, 0, 0);
    }
    __syncthreads();
  }
  float4 bia[4];
#pragma unroll
  for (int ni = 0; ni < 4; ++ni)
    bia[ni] = *(const float4*)(bias + bn + wn + ni * 16 + l4 * 4);
#pragma unroll
  for (int mi = 0; mi < 4; ++mi) {
    int row = bm + wm + mi * 16 + l15;
    if (row >= M_ROWS) continue;
#pragma unroll
    for (int ni = 0; ni < 4; ++ni) {
      int col = bn + wn + ni * 16 + l4 * 4;
      float v0 = acc[ni][mi][0] + bia[ni].x;
      float v1 = acc[ni][mi][1] + bia[ni].y;
      float v2 = acc[ni][mi][2] + bia[ni].z;
      float v3 = acc[ni][mi][3] + bia[ni].w;
      if (z == 0 || z == 3) {
        ushort4 pk;
        pk.x = f2bf(v0);
        pk.y = f2bf(v1);
        pk.z = f2bf(v2);
        pk.w = f2bf(v3);
        unsigned short* dst = (z == 0) ? oqb : osb;
        *(ushort4*)(dst + (size_t)row * D + col) = pk;
      } else {
        unsigned pk8 = f4_to_fp8x4(v0, v1, v2, v3);
        *(unsigned*)(okv + (size_t)(2 * row + (z - 1)) * D + col) = pk8;
      }
    }
  }
}

// ---- combined-graph CSR build ----
__global__ void k_hist(const int* __restrict__ dstI, const int* __restrict__ dstJ,
                       int* __restrict__ cnt) {
  int e = blockIdx.x * blockDim.x + threadIdx.x;
  if (e >= 2 * N_EDGES) return;
  int d = (e < N_EDGES) ? dstI[e] : (dstJ[e - N_EDGES] + N_NODES);
  atomicAdd(&cnt[d], 1);
}

__global__ __launch_bounds__(1024) void k_scan(const int* __restrict__ cnt,
                                               int* __restrict__ start,
                                               int* __restrict__ cursor) {
  __shared__ int sh[1024];
  __shared__ int carry_sh;
  int tid = threadIdx.x;
  if (tid == 0) {
    carry_sh = 0;
    start[0] = 0;
  }
  __syncthreads();
  for (int base = 0; base < M_ROWS; base += 1024) {
    int idx = base + tid;
    int v = (idx < M_ROWS) ? cnt[idx] : 0;
    sh[tid] = v;
    __syncthreads();
    for (int off = 1; off < 1024; off <<= 1) {
      int t = (tid >= off) ? sh[tid - off] : 0;
      __syncthreads();
      sh[tid] += t;
      __syncthreads();
    }
    int incl = sh[tid] + carry_sh;
    if (idx < M_ROWS) {
      start[idx + 1] = incl;
      cursor[idx] = incl - v;
    }
    __syncthreads();
    if (tid == 1023) carry_sh = incl;
    __syncthreads();
  }
}

// scatter + gather edge attrs into CSR order (eaS)
__global__ void k_scatter(const int* __restrict__ srcI, const int* __restrict__ dstI,
                          const int* __restrict__ srcJ, const int* __restrict__ dstJ,
                          const float* __restrict__ eaI, const float* __restrict__ eaJ,
                          int* __restrict__ cursor, int* __restrict__ srcS,
                          float* __restrict__ eaS) {
  int e = blockIdx.x * blockDim.x + threadIdx.x;
  if (e >= 2 * N_EDGES) return;
  int s, d;
  const float* eap;
  if (e < N_EDGES) {
    s = srcI[e];
    d = dstI[e];
    eap = eaI + (size_t)e * ED_IN;
  } else {
    s = srcJ[e - N_EDGES] + N_NODES;
    d = dstJ[e - N_EDGES] + N_NODES;
    eap = eaJ + (size_t)(e - N_EDGES) * ED_IN;
  }
  int pos = atomicAdd(&cursor[d], 1);
  srcS[pos] = s;
  float4 a0 = *(const float4*)eap;
  float4 a1 = *(const float4*)(eap + 4);
  *(float4*)(eaS + (size_t)pos * ED_IN) = a0;
  *(float4*)(eaS + (size_t)pos * ED_IN + 4) = a1;
}

// ---- fused edge phase (R12/R13 proven config): one wave per node; two
// 32-lane groups split the edge list (stride 2), each unrolled by 2, srcS
// prefetch; fp8 k/v gathers with deferred v decode; Gc prologue split across
// groups; online softmax; width-64 merge.
__global__ __launch_bounds__(256) void k_edge_fused(
    unsigned char* __restrict__ hf8, unsigned short* __restrict__ hbf,
    const unsigned short* __restrict__ sbf, const unsigned short* __restrict__ qb16,
    const unsigned char* __restrict__ kvf8, const float* __restrict__ eaS,
    const float* __restrict__ We, const int* __restrict__ srcS,
    const int* __restrict__ start, int do_relu, int write_bf) {
  int w = blockIdx.x * 4 + (threadIdx.x >> 6);
  if (w >= M_ROWS) return;
  int l64 = threadIdx.x & 63;
  int g = l64 >> 5, lane = l64 & 31;
  const int s0 = start[w], s1 = start[w + 1];
  const int deg = s1 - s0;
  const int EMAX = 2 * N_EDGES - 1;

  float4 qr[5];
#pragma unroll
  for (int i = 0; i < 5; ++i)
    qr[i] = cvt4(*(const ushort4*)(qb16 + (size_t)w * D + i * 128 + 4 * lane));

  // Gc split: group g computes c = 4g+j (j=0..3), shared via width-64 shfl.
  float gv = 0.f;
#pragma unroll
  for (int j = 0; j < 4; ++j) {
    const float* wr = We + (4 * g + j) * D;
    float p = 0.f;
#pragma unroll
    for (int i = 0; i < 5; ++i) {
      float4 wv = *(const float4*)(wr + i * 128 + 4 * lane);
      p += qr[i].x * wv.x + qr[i].y * wv.y + qr[i].z * wv.z + qr[i].w * wv.w;
    }
#pragma unroll
    for (int m = 1; m < 32; m <<= 1) p += __shfl_xor(p, m, 32);
    if (lane == j) gv = p;
  }
  float Gc = 0.f;
  {
    int src = (lane < 4) ? lane : (32 + lane - 4);
    float tg = __shfl(gv, src, 64);
    if (lane < ED_IN) Gc = tg;
  }

  float mx = NEGBIG, Sp = 0.f, Sea = 0.f;
  float4 acc[5];
#pragma unroll
  for (int i = 0; i < 5; ++i) acc[i] = make_float4(0.f, 0.f, 0.f, 0.f);

  int p0 = s0 + g, p1 = p0 + 2;
  int c0 = min(p0, EMAX), c1 = min(p1, EMAX);
  int sj0 = srcS[c0], sj1 = srcS[c1];
  const int U = (deg + 3) >> 2;
  for (int u = 0; u < U; ++u) {
    bool ok0 = p0 < s1, ok1 = p1 < s1;
    int cc0 = c0, cc1 = c1;
    int tj0 = sj0, tj1 = sj1;
    p0 += 4;
    p1 += 4;
    c0 = min(p0, EMAX);
    c1 = min(p1, EMAX);
    sj0 = srcS[c0];
    sj1 = srcS[c1];

    const unsigned char* r0 = kvf8 + (size_t)tj0 * 2 * D;
    const unsigned char* r1 = kvf8 + (size_t)tj1 * 2 * D;
    unsigned kp0[5], kp1[5], vp0[5], vp1[5];
#pragma unroll
    for (int i = 0; i < 5; ++i) {
      int off = i * 128 + 4 * lane;
      kp0[i] = *(const unsigned*)(r0 + off);
      kp1[i] = *(const unsigned*)(r1 + off);
      vp0[i] = *(const unsigned*)(r0 + D + off);
      vp1[i] = *(const unsigned*)(r1 + D + off);
    }
    float ea0 = (lane < ED_IN) ? eaS[(size_t)cc0 * ED_IN + lane] : 0.f;
    float ea1 = (lane < ED_IN) ? eaS[(size_t)cc1 * ED_IN + lane] : 0.f;
    float part0 = ea0 * Gc, part1 = ea1 * Gc;
#pragma unroll
    for (int i = 0; i < 5; ++i) {
      float4 k0 = fp8x4_to_f4(kp0[i]);
      float4 k1 = fp8x4_to_f4(kp1[i]);
      part0 += qr[i].x * k0.x + qr[i].y * k0.y + qr[i].z * k0.z + qr[i].w * k0.w;
      part1 += qr[i].x * k1.x + qr[i].y * k1.y + qr[i].z * k1.z + qr[i].w * k1.w;
    }
#pragma unroll
    for (int m = 1; m < 32; m <<= 1) {
      part0 += __shfl_xor(part0, m, 32);
      part1 += __shfl_xor(part1, m, 32);
    }
    float sc0 = ok0 ? part0 * SCORE_SCALE : NEGBIG;
    float sc1 = ok1 ? part1 * SCORE_SCALE : NEGBIG;
    float m2 = fmaxf(sc0, sc1);
    if (m2 > mx) {
      float cs = __expf(mx - m2);
      float pA = __expf(sc0 - m2);
      float pB = __expf(sc1 - m2);
      mx = m2;
      Sp = Sp * cs + pA + pB;
      Sea = Sea * cs + pA * ea0 + pB * ea1;
#pragma unroll
      for (int i = 0; i < 5; ++i) {
        float4 v0 = fp8x4_to_f4(vp0[i]);
        float4 v1 = fp8x4_to_f4(vp1[i]);
        acc[i].x = acc[i].x * cs + pA * v0.x + pB * v1.x;
        acc[i].y = acc[i].y * cs + pA * v0.y + pB * v1.y;
        acc[i].z = acc[i].z * cs + pA * v0.z + pB * v1.z;
        acc[i].w = acc[i].w * cs + pA * v0.w + pB * v1.w;
      }
    } else {
      float pA = __expf(sc0 - mx);
      float pB = __expf(sc1 - mx);
      Sp += pA + pB;
      Sea += pA * ea0 + pB * ea1;
#pragma unroll
      for (int i = 0; i < 5; ++i) {
        float4 v0 = fp8x4_to_f4(vp0[i]);
        float4 v1 = fp8x4_to_f4(vp1[i]);
        acc[i].x += pA * v0.x + pB * v1.x;
        acc[i].y += pA * v0.y + pB * v1.y;
        acc[i].z += pA * v0.z + pB * v1.z;
        acc[i].w += pA * v0.w + pB * v1.w;
      }
    }
  }

  // merge the two groups' online-softmax states
  float mo = __shfl_xor(mx, 32);
  float mn = fmaxf(mx, mo);
  float a = __expf(mx - mn);
  float b = __expf(mo - mn);
  float Spo = __shfl_xor(Sp, 32);
  Sp = Sp * a + Spo * b;
  float Seao = __shfl_xor(Sea, 32);
  Sea = Sea * a + Seao * b;
#pragma unroll
  for (int i = 0; i < 5; ++i) {
    float ox = __shfl_xor(acc[i].x, 32);
    float oy = __shfl_xor(acc[i].y, 32);
    float oz = __shfl_xor(acc[i].z, 32);
    float ow = __shfl_xor(acc[i].w, 32);
    acc[i].x = acc[i].x * a + ox * b;
    acc[i].y = acc[i].y * a + oy * b;
    acc[i].z = acc[i].z * a + oz * b;
    acc[i].w = acc[i].w * a + ow * b;
  }
  float inv = 1.0f / (Sp + 1e-16f);
  float seac[ED_IN];
#pragma unroll
  for (int c = 0; c < ED_IN; ++c) seac[c] = __shfl(Sea, c, 32);

  for (int i = g; i < 5; i += 2) {
    int d = i * 128 + 4 * lane;
    float4 term = acc[i];
#pragma unroll
    for (int c = 0; c < ED_IN; ++c) {
      float4 wv = *(const float4*)(We + c * D + d);
      term.x += seac[c] * wv.x;
      term.y += seac[c] * wv.y;
      term.z += seac[c] * wv.z;
      term.w += seac[c] * wv.w;
    }
    ushort4 sv = *(const ushort4*)(sbf + (size_t)w * D + d);
    float vx = bf2f(sv.x) + term.x * inv;
    float vy = bf2f(sv.y) + term.y * inv;
    float vz = bf2f(sv.z) + term.z * inv;
    float vw = bf2f(sv.w) + term.w * inv;
    if (do_relu) {
      vx = fmaxf(vx, 0.f);
      vy = fmaxf(vy, 0.f);
      vz = fmaxf(vz, 0.f);
      vw = fmaxf(vw, 0.f);
    }
    if (write_bf) {
      ushort4 hb;
      hb.x = f2bf(vx);
      hb.y = f2bf(vy);
      hb.z = f2bf(vz);
      hb.w = f2bf(vw);
      *(ushort4*)(hbf + (size_t)w * D + d) = hb;
    } else {
      *(unsigned*)(hf8 + (size_t)w * D + d) = f4_to_fp8x4(vx, vy, vz, vw);
    }
  }
}

// per-batch node ranges via binary search (batch arrays are sorted)
__global__ void k_ranges(const int* __restrict__ batI, const int* __restrict__ batJ,
                         int* __restrict__ rng) {
  int b = threadIdx.x;
  if (b > 2 * NB) return;
  if (b == 2 * NB) {
    rng[b] = M_ROWS;
    return;
  }
  const int* bat = (b < NB) ? batI : batJ;
  int tgt = (b < NB) ? b : b - NB;
  int lo = 0, hi = N_NODES;
  while (lo < hi) {
    int mid = (lo + hi) >> 1;
    if (bat[mid] < tgt) lo = mid + 1;
    else hi = mid;
  }
  rng[b] = lo + ((b < NB) ? 0 : N_NODES);
}

// segmented pool: block b sums rows [rng[b], rng[b+1]) — no atomics
__global__ __launch_bounds__(256) void k_pool_seg(const unsigned short* __restrict__ hbf,
                                                  const int* __restrict__ rng,
                                                  float* __restrict__ pooled) {
  int b = blockIdx.x;
  int lo = rng[b], hi = rng[b + 1];
  int ch = threadIdx.x;  // ushort4 chunk id, 0..159
  if (ch >= 160) return;
  float4 s = make_float4(0.f, 0.f, 0.f, 0.f);
  for (int n = lo; n < hi; ++n) {
    ushort4 v = *(const ushort4*)(hbf + (size_t)n * D + ch * 4);
    s.x += bf2f(v.x);
    s.y += bf2f(v.y);
    s.z += bf2f(v.z);
    s.w += bf2f(v.w);
  }
  *(float4*)(pooled + (size_t)b * D + ch * 4) = s;
}

// head: LayerNorm -> @Wemb + bemb -> ReLU.  grid (2NB, 5), 128 threads.
__global__ __launch_bounds__(128) void k_head(const float* __restrict__ pooled,
                                              const float* __restrict__ gam,
                                              const float* __restrict__ bet,
                                              const float* __restrict__ Wemb,
                                              const float* __restrict__ bemb,
                                              float* __restrict__ z) {
  __shared__ float sh[D];
  __shared__ float red[2];
  int b = blockIdx.x, seg = blockIdx.y, tid = threadIdx.x;
  float local = 0.f;
#pragma unroll
  for (int c = tid; c < D; c += 128) {
    float val = pooled[(size_t)b * D + c];
    sh[c] = val;
    local += val;
  }
#pragma unroll
  for (int off = 32; off > 0; off >>= 1) local += __shfl_down(local, off);
  if ((tid & 63) == 0) red[tid >> 6] = local;
  __syncthreads();
  float mu = (red[0] + red[1]) * (1.0f / D);
  __syncthreads();
  float lv = 0.f;
#pragma unroll
  for (int c = tid; c < D; c += 128) {
    float t2 = sh[c] - mu;
    lv += t2 * t2;
  }
#pragma unroll
  for (int off = 32; off > 0; off >>= 1) lv += __shfl_down(lv, off);
  if ((tid & 63) == 0) red[tid >> 6] = lv;
  __syncthreads();
  float var = (red[0] + red[1]) * (1.0f / D);
  float rstd = rsqrtf(var + 1e-5f);
  __syncthreads();
#pragma unroll
  for (int c = tid; c < D; c += 128) sh[c] = (sh[c] - mu) * rstd * gam[c] + bet[c];
  __syncthreads();
  int d = seg * 128 + tid;
  float a0 = 0.f, a1 = 0.f, a2 = 0.f, a3 = 0.f;
  for (int c = 0; c < D; c += 4) {
    a0 += sh[c] * Wemb[(size_t)c * D + d];
    a1 += sh[c + 1] * Wemb[(size_t)(c + 1) * D + d];
    a2 += sh[c + 2] * Wemb[(size_t)(c + 2) * D + d];
    a3 += sh[c + 3] * Wemb[(size_t)(c + 3) * D + d];
  }
  z[(size_t)b * D + d] = fmaxf((a0 + a1) + (a2 + a3) + bemb[d], 0.f);
}

__global__ void k_cosine(const float* __restrict__ zi, const float* __restrict__ zj,
                         float* __restrict__ out) {
  int b = blockIdx.x, lane = threadIdx.x;
  float dot = 0.f, ni = 0.f, nj = 0.f;
  for (int d = lane; d < D; d += 64) {
    float a = zi[(size_t)b * D + d], c = zj[(size_t)b * D + d];
    dot += a * c;
    ni += a * a;
    nj += c * c;
  }
#pragma unroll
  for (int off = 32; off > 0; off >>= 1) {
    dot += __shfl_down(dot, off);
    ni += __shfl_down(ni, off);
    nj += __shfl_down(nj, off);
  }
  if (lane == 0)
    out[b] = dot / (fmaxf(sqrtf(ni), 1e-8f) * fmaxf(sqrtf(nj), 1e-8f));
}

extern "C" void kernel_launch(void* const* d_in, const int* in_sizes, int n_in,
                              void* d_out, int out_size, void* d_ws, size_t ws_size,
                              hipStream_t stream) {
  (void)in_sizes; (void)n_in; (void)out_size; (void)ws_size;
  const float* xI = (const float*)d_in[0];
  const int* eiI = (const int*)d_in[1];
  const float* eaI = (const float*)d_in[2];
  const int* batI = (const int*)d_in[3];
  const float* xJ = (const float*)d_in[4];
  const int* eiJ = (const int*)d_in[5];
  const float* eaJ = (const float*)d_in[6];
  const int* batJ = (const int*)d_in[7];
  const float* W0q = (const float*)d_in[8];
  const float* b0q = (const float*)d_in[9];
  const float* W0k = (const float*)d_in[10];
  const float* b0k = (const float*)d_in[11];
  const float* W0v = (const float*)d_in[12];
  const float* b0v = (const float*)d_in[13];
  const float* W0e = (const float*)d_in[14];
  const float* W0s = (const float*)d_in[15];
  const float* b0s = (const float*)d_in[16];
  const float* Wq = (const float*)d_in[17];
  const float* bq = (const float*)d_in[18];
  const float* Wk = (const float*)d_in[19];
  const float* bk = (const float*)d_in[20];
  const float* Wv = (const float*)d_in[21];
  const float* bv = (const float*)d_in[22];
  const float* We = (const float*)d_in[23];
  const float* Ws = (const float*)d_in[24];
  const float* bs = (const float*)d_in[25];
  const float* ln_g = (const float*)d_in[26];
  const float* ln_b = (const float*)d_in[27];
  const float* Wemb = (const float*)d_in[28];
  const float* bemb = (const float*)d_in[29];

  const size_t ND2 = (size_t)M_ROWS * D;
  float* pooled = (float*)d_ws;                  // 2NB*D
  float* z = pooled + (size_t)2 * NB * D;        // 2NB*D
  float* eaS = z + (size_t)2 * NB * D;           // 2E*8
  unsigned short* qbf = (unsigned short*)(eaS + (size_t)2 * N_EDGES * ED_IN);
  unsigned char* kvf8 = (unsigned char*)(qbf + ND2);   // 2*ND2 bytes (k/v fp8)
  unsigned char* hf8 = kvf8 + 2 * ND2;                 // ND2 bytes (h fp8)
  unsigned short* hbf = (unsigned short*)(hf8 + ND2);  // ND2 (also hf8 OOB pad)
  unsigned short* sbf = hbf + ND2;               // ND2
  unsigned char* Wt8 = (unsigned char*)(sbf + ND2);    // 20*D*D bytes
  int* cnt = (int*)(Wt8 + (size_t)(NLAYERS - 1) * 4 * D * D);  // 2N
  int* start = cnt + M_ROWS;                     // 2N+1
  int* cursor = start + M_ROWS + 1;              // 2N
  int* srcS = cursor + M_ROWS;                   // 2E
  int* rng = srcS + 2 * N_EDGES;                 // 2NB+1

  const int* srcI = eiI;
  const int* dstI = eiI + N_EDGES;
  const int* srcJ = eiJ;
  const int* dstJ = eiJ + N_EDGES;

  dim3 gLin((M_ROWS * D + 255) / 256);
  dim3 gGemm(8 * 20 * 20);
  dim3 gEdge((M_ROWS + 3) / 4);
  dim3 gE((2 * N_EDGES + 255) / 256);

  k_wprep<<<dim3(D / 32, D / 32, (NLAYERS - 1) * 4), 256, 0, stream>>>(Wq, Wk, Wv, Ws, Wt8);

  // combined CSR (+ ea gather into CSR order) + batch ranges
  hipMemsetAsync(cnt, 0, M_ROWS * sizeof(int), stream);
  k_hist<<<gE, 256, 0, stream>>>(dstI, dstJ, cnt);
  k_scan<<<1, 1024, 0, stream>>>(cnt, start, cursor);
  k_scatter<<<gE, 256, 0, stream>>>(srcI, dstI, srcJ, dstJ, eaI, eaJ, cursor,
                                    srcS, eaS);
  k_ranges<<<1, 192, 0, stream>>>(batI, batJ, rng);

  // layer 0 (single fused projection pass)
  k_lin4<<<gLin, 256, 0, stream>>>(xI, xJ, W0q, b0q, W0k, b0k, W0v, b0v, W0s,
                                   b0s, qbf, kvf8, sbf);
  k_edge_fused<<<gEdge, 256, 0, stream>>>(hf8, hbf, sbf, qbf, kvf8, eaS, W0e,
                                          srcS, start, 1, 0);

  // layers 1..5
  for (int l = 0; l < NLAYERS - 1; ++l) {
    const unsigned char* WtL = Wt8 + (size_t)l * 4 * D * D;
    const float* Wel = We + (size_t)l * ED_IN * D;
    int last = (l == NLAYERS - 2);
    k_gemm_fp8<<<gGemm, 256, 0, stream>>>(
        hf8, WtL, bq + (size_t)l * D, bk + (size_t)l * D, bv + (size_t)l * D,
        bs + (size_t)l * D, qbf, kvf8, sbf);
    k_edge_fused<<<gEdge, 256, 0, stream>>>(hf8, hbf, sbf, qbf, kvf8, eaS, Wel,
                                            srcS, start, last ? 0 : 1,
                                            last ? 1 : 0);
  }

  k_pool_seg<<<2 * NB, 256, 0, stream>>>(hbf, rng, pooled);
  k_head<<<dim3(2 * NB, 5), 128, 0, stream>>>(pooled, ln_g, ln_b, Wemb, bemb, z);
  k_cosine<<<NB, 64, 0, stream>>>(z, z + (size_t)NB * D, (float*)d_out);
}